// Round 4
// baseline (231.774 us; speedup 1.0000x reference)
//
#include <hip/hip_runtime.h>
#include <stdint.h>

typedef __bf16 bf16x8 __attribute__((ext_vector_type(8)));
typedef float  f32x4  __attribute__((ext_vector_type(4)));

#define HH 384
#define WW 384
#define NPIX (HH*WW)
#define NC 3
#define NPATCH 576
#define EMB 768
#define PLEN 768
#define MLOC 32
#define KSTEPS 24
#define NLOC (64*576)
#define NTILES (NLOC/MLOC)       /* 1152 */
#define NT1 4                    /* GEMM1 n-tiles per wave (8 waves x 4 = 32) */
#define NT2 6                    /* GEMM2 n-tiles per wave (8 waves x 6 = 48) */
#define W1_UNITS (32*KSTEPS*64)  /* 16B-units for offset weights */
#define W2_UNITS (48*KSTEPS*64)  /* 16B-units for proj weights   */
#define W2_OFF   (W1_UNITS*8)
#define CTR_OFF  ((size_t)(W1_UNITS + W2_UNITS) * 16)   /* counter byte offset in ws */
#define PERSIST_BLOCKS 512

__device__ __forceinline__ uint16_t f2bf(float f) {
    uint32_t u = __builtin_bit_cast(uint32_t, f);
    u += 0x7FFFu + ((u >> 16) & 1u);
    return (uint16_t)(u >> 16);
}
__device__ __forceinline__ uint32_t pk2(float a, float b) {
    return (uint32_t)f2bf(a) | ((uint32_t)f2bf(b) << 16);
}
__device__ __forceinline__ float bf2f(uint16_t u) {
    return __builtin_bit_cast(float, (uint32_t)u << 16);
}

// Pre-convert both weight matrices to bf16 in MFMA-fragment order:
// unit u -> (nt, ks, lane); n = nt*16 + (lane&15), k = ks*32 + (lane>>4)*8 + e
__global__ __launch_bounds__(256)
void convert_weights(const float* __restrict__ offw, const float* __restrict__ projw,
                     uint16_t* __restrict__ wz) {
    int u = blockIdx.x * 256 + threadIdx.x;
    const float* src;
    int uu;
    if (u < W1_UNITS) { src = offw; uu = u; }
    else              { src = projw; uu = u - W1_UNITS; }
    int lane = uu & 63;
    int t    = uu >> 6;
    int ks   = t % KSTEPS;
    int nt   = t / KSTEPS;
    int n    = nt * 16 + (lane & 15);
    int k0   = ks * 32 + (lane >> 4) * 8;
    const float4* s4 = (const float4*)(src + (size_t)n * PLEN + k0);
    float4 v0 = s4[0], v1 = s4[1];
    uint4 w;
    w.x = pk2(v0.x, v0.y); w.y = pk2(v0.z, v0.w);
    w.z = pk2(v1.x, v1.y); w.w = pk2(v1.z, v1.w);
    *(uint4*)(wz + (size_t)u * 8) = w;
}

template<bool USE_WS, bool PERSIST>
__global__ __launch_bounds__(512, 4)
void fused_kernel(const float* __restrict__ pix,
                  const float* __restrict__ offw,
                  const float* __restrict__ offb,
                  const float* __restrict__ projw,
                  const float* __restrict__ projb,
                  const uint16_t* __restrict__ wz,
                  unsigned int* __restrict__ ctr,
                  float* __restrict__ out) {
    __shared__ __align__(16) uint16_t As[MLOC][PLEN];   // 48 KB, XOR-swizzled rows
    __shared__ int s_tile;

    const int tid  = threadIdx.x;
    const int wv   = tid >> 6;
    const int lane = tid & 63;
    const int lr   = lane & 15;
    const int lg   = lane >> 4;
    const int sw0  = (lr & 7) << 3;
    const int even = ((lane & 1) == 0);

    for (;;) {
        int tile;
        if (PERSIST) {
            if (tid == 0) s_tile = (int)atomicAdd(ctr, 1u);
            __syncthreads();                 // also fences As reuse across tiles
            tile = s_tile;
            if (tile >= NTILES) break;
        } else {
            int bid = (int)blockIdx.x;       // bijective XCD swizzle: 1152 = 8 x 144
            tile = (bid & 7) * 144 + (bid >> 3);
        }

        const int loc0 = tile * MLOC;
        const int bimg = loc0 / NPATCH;
        const int p0   = loc0 - bimg * NPATCH;
        const float* __restrict__ pb = pix + (size_t)bimg * NC * NPIX;

        // ---------------- Phase A: stage 32 patches (f32 -> bf16, swizzled) ----
        #pragma unroll
        for (int uu = 0; uu < 6; ++uu) {
            int unit = tid + uu * 512;             // 0..3071
            int loc  = unit / 96;
            int k8   = (unit - loc * 96) * 8;
            int c  = k8 >> 8;
            int i  = (k8 >> 4) & 15;
            int j  = k8 & 15;
            int p  = p0 + loc;
            int ho = p / 24;
            int wo = p - ho * 24;
            const float* g = pb + ((size_t)c * HH + ho * 16 + i) * WW + wo * 16 + j;
            float4 v0 = *(const float4*)g;
            float4 v1 = *(const float4*)(g + 4);
            uint4 w;
            w.x = pk2(v0.x, v0.y); w.y = pk2(v0.z, v0.w);
            w.z = pk2(v1.x, v1.y); w.w = pk2(v1.z, v1.w);
            *(uint4*)&As[loc][k8 ^ ((loc & 7) << 3)] = w;
        }

        // ---------------- GEMM1: offsets [32 x 512], B double-buffered ---------
        auto ldb1 = [&](int ntg, int ks) -> bf16x8 {
            if (USE_WS) {
                return *(const bf16x8*)(wz + ((size_t)((ntg * KSTEPS + ks) * 64 + lane)) * 8);
            } else {
                int n = ntg * 16 + lr;
                const float4* s4 = (const float4*)(offw + (size_t)n * PLEN + ks * 32 + lg * 8);
                float4 v0 = s4[0], v1 = s4[1];
                uint4 uq = {pk2(v0.x,v0.y), pk2(v0.z,v0.w), pk2(v1.x,v1.y), pk2(v1.z,v1.w)};
                return __builtin_bit_cast(bf16x8, uq);
            }
        };
        bf16x8 b1a[NT1], b1b[NT1];
        #pragma unroll
        for (int nt = 0; nt < NT1; ++nt) b1a[nt] = ldb1(wv * NT1 + nt, 0);
        __syncthreads();                       // stage visible

        f32x4 acc1[2][NT1];
        #pragma unroll
        for (int nt = 0; nt < NT1; ++nt) {
            float bz = offb[(wv * NT1 + nt) * 16 + lr];
            f32x4 z = {bz, bz, bz, bz};
            acc1[0][nt] = z; acc1[1][nt] = z;
        }
        #pragma unroll 1
        for (int ks2 = 0; ks2 < KSTEPS / 2; ++ks2) {
            const int ks0 = ks2 * 2;
            {
                #pragma unroll
                for (int nt = 0; nt < NT1; ++nt) b1b[nt] = ldb1(wv * NT1 + nt, ks0 + 1);
                int ke = (ks0 * 32 + lg * 8) ^ sw0;
                bf16x8 a0 = *(const bf16x8*)&As[lr][ke];
                bf16x8 a1 = *(const bf16x8*)&As[16 + lr][ke];
                __builtin_amdgcn_s_setprio(1);
                #pragma unroll
                for (int nt = 0; nt < NT1; ++nt) {
                    acc1[0][nt] = __builtin_amdgcn_mfma_f32_16x16x32_bf16(a0, b1a[nt], acc1[0][nt], 0, 0, 0);
                    acc1[1][nt] = __builtin_amdgcn_mfma_f32_16x16x32_bf16(a1, b1a[nt], acc1[1][nt], 0, 0, 0);
                }
                __builtin_amdgcn_s_setprio(0);
            }
            {
                int ksn = (ks0 + 2 < KSTEPS) ? ks0 + 2 : 0;
                #pragma unroll
                for (int nt = 0; nt < NT1; ++nt) b1a[nt] = ldb1(wv * NT1 + nt, ksn);
                int ke = ((ks0 + 1) * 32 + lg * 8) ^ sw0;
                bf16x8 a0 = *(const bf16x8*)&As[lr][ke];
                bf16x8 a1 = *(const bf16x8*)&As[16 + lr][ke];
                __builtin_amdgcn_s_setprio(1);
                #pragma unroll
                for (int nt = 0; nt < NT1; ++nt) {
                    acc1[0][nt] = __builtin_amdgcn_mfma_f32_16x16x32_bf16(a0, b1b[nt], acc1[0][nt], 0, 0, 0);
                    acc1[1][nt] = __builtin_amdgcn_mfma_f32_16x16x32_bf16(a1, b1b[nt], acc1[1][nt], 0, 0, 0);
                }
                __builtin_amdgcn_s_setprio(0);
            }
        }
        // NOTE: no barrier needed here — gather below only READS As (writes deferred).

        // ---------------- Pair (dy,dx) in-register via shfl_xor ----------------
        // n=2q is dy(q), n=2q+1 is dx(q). Even lanes keep local tiles {0,1},
        // odd lanes {2,3}; each lane owns 2 tiles (s in {0,1}).
        float dyg[2][2][4], dxg[2][2][4];
        #pragma unroll
        for (int nt = 0; nt < NT1; ++nt)
          #pragma unroll
          for (int mt = 0; mt < 2; ++mt)
            #pragma unroll
            for (int r = 0; r < 4; ++r) {
                float v  = acc1[mt][nt][r];
                float pv = __shfl_xor(v, 1);
                if ((nt < 2) == (even != 0)) {
                    int s = nt & 1;
                    dyg[s][mt][r] = even ? v  : pv;
                    dxg[s][mt][r] = even ? pv : v;
                }
            }

        // ---------------- Phase C1: gather (LDS patch reads + global fallback) -
        const int ntb  = wv * NT1 + (even ? 0 : 2);
        const int qlow = lr >> 1;
        uint32_t smp01[2][2][4];   // packed bf16 (ch0, ch1)
        uint32_t smp2 [2][2][4];   // bf16 ch2
        #pragma unroll
        for (int s = 0; s < 2; ++s) {
            int q  = (ntb + s) * 8 + qlow;   // patch pixel 0..255
            int qi = q >> 4;
            int qj = q & 15;
            #pragma unroll
            for (int mt = 0; mt < 2; ++mt)
              #pragma unroll
              for (int r = 0; r < 4; ++r) {
                int locl = mt * 16 + lg * 4 + r;
                int p  = p0 + locl;
                int ho = p / 24;
                int wo = p - ho * 24;
                float py = (float)(ho * 16 + qi) + dyg[s][mt][r];
                float px = (float)(wo * 16 + qj) + dxg[s][mt][r];
                float y0f = floorf(py), x0f = floorf(px);
                float wy1 = py - y0f, wy0 = 1.f - wy1;
                float wx1 = px - x0f, wx0 = 1.f - wx1;
                int y0 = (int)y0f, x0 = (int)x0f;
                float s0 = 0.f, s1 = 0.f, s2 = 0.f;
                #pragma unroll
                for (int cy = 0; cy < 2; ++cy) {
                    int yy = y0 + cy;
                    if ((unsigned)yy < (unsigned)HH) {
                        float wy = cy ? wy1 : wy0;
                        #pragma unroll
                        for (int cx = 0; cx < 2; ++cx) {
                            int xx = x0 + cx;
                            if ((unsigned)xx < (unsigned)WW) {
                                float w = wy * (cx ? wx1 : wx0);
                                int li = ((yy >> 4) * 24 + (xx >> 4)) - p0;
                                float v0, v1, v2;
                                if ((unsigned)li < (unsigned)MLOC) {
                                    int kk  = ((yy & 15) << 4) | (xx & 15);
                                    int sw2 = (li & 7) << 3;
                                    v0 = bf2f(As[li][(kk      ) ^ sw2]);
                                    v1 = bf2f(As[li][(kk + 256) ^ sw2]);
                                    v2 = bf2f(As[li][(kk + 512) ^ sw2]);
                                } else {
                                    const float* cp = pb + yy * WW + xx;
                                    v0 = cp[0]; v1 = cp[NPIX]; v2 = cp[2 * NPIX];
                                }
                                s0 += w * v0; s1 += w * v1; s2 += w * v2;
                            }
                        }
                    }
                }
                smp01[s][mt][r] = pk2(s0, s1);
                smp2 [s][mt][r] = f2bf(s2);
              }
        }
        __syncthreads();   // all gather reads of As complete

        // ---------------- Phase C2: write sampled values into As ---------------
        #pragma unroll
        for (int s = 0; s < 2; ++s) {
            int q = (ntb + s) * 8 + qlow;
            #pragma unroll
            for (int mt = 0; mt < 2; ++mt)
              #pragma unroll
              for (int r = 0; r < 4; ++r) {
                int locl = mt * 16 + lg * 4 + r;
                int swl = (locl & 7) << 3;
                uint32_t p01 = smp01[s][mt][r];
                As[locl][(      q) ^ swl] = (uint16_t)p01;
                As[locl][(256 + q) ^ swl] = (uint16_t)(p01 >> 16);
                As[locl][(512 + q) ^ swl] = (uint16_t)smp2[s][mt][r];
              }
        }

        // ---------------- GEMM2: out [32 x 768], B double-buffered -------------
        auto ldb2 = [&](int ntg, int ks) -> bf16x8 {
            if (USE_WS) {
                return *(const bf16x8*)(wz + W2_OFF + ((size_t)((ntg * KSTEPS + ks) * 64 + lane)) * 8);
            } else {
                int n = ntg * 16 + lr;
                const float4* s4 = (const float4*)(projw + (size_t)n * PLEN + ks * 32 + lg * 8);
                float4 v0 = s4[0], v1 = s4[1];
                uint4 uq = {pk2(v0.x,v0.y), pk2(v0.z,v0.w), pk2(v1.x,v1.y), pk2(v1.z,v1.w)};
                return __builtin_bit_cast(bf16x8, uq);
            }
        };
        bf16x8 b2a[NT2], b2b[NT2];
        #pragma unroll
        for (int nt = 0; nt < NT2; ++nt) b2a[nt] = ldb2(wv * NT2 + nt, 0);
        __syncthreads();                       // sampled writes visible

        f32x4 acc2[2][NT2];
        #pragma unroll
        for (int nt = 0; nt < NT2; ++nt) {
            float bz = projb[(wv * NT2 + nt) * 16 + lr];
            f32x4 z = {bz, bz, bz, bz};
            acc2[0][nt] = z; acc2[1][nt] = z;
        }
        #pragma unroll 1
        for (int ks2 = 0; ks2 < KSTEPS / 2; ++ks2) {
            const int ks0 = ks2 * 2;
            {
                #pragma unroll
                for (int nt = 0; nt < NT2; ++nt) b2b[nt] = ldb2(wv * NT2 + nt, ks0 + 1);
                int ke = (ks0 * 32 + lg * 8) ^ sw0;
                bf16x8 a0 = *(const bf16x8*)&As[lr][ke];
                bf16x8 a1 = *(const bf16x8*)&As[16 + lr][ke];
                __builtin_amdgcn_s_setprio(1);
                #pragma unroll
                for (int nt = 0; nt < NT2; ++nt) {
                    acc2[0][nt] = __builtin_amdgcn_mfma_f32_16x16x32_bf16(a0, b2a[nt], acc2[0][nt], 0, 0, 0);
                    acc2[1][nt] = __builtin_amdgcn_mfma_f32_16x16x32_bf16(a1, b2a[nt], acc2[1][nt], 0, 0, 0);
                }
                __builtin_amdgcn_s_setprio(0);
            }
            {
                int ksn = (ks0 + 2 < KSTEPS) ? ks0 + 2 : 0;
                #pragma unroll
                for (int nt = 0; nt < NT2; ++nt) b2a[nt] = ldb2(wv * NT2 + nt, ksn);
                int ke = ((ks0 + 1) * 32 + lg * 8) ^ sw0;
                bf16x8 a0 = *(const bf16x8*)&As[lr][ke];
                bf16x8 a1 = *(const bf16x8*)&As[16 + lr][ke];
                __builtin_amdgcn_s_setprio(1);
                #pragma unroll
                for (int nt = 0; nt < NT2; ++nt) {
                    acc2[0][nt] = __builtin_amdgcn_mfma_f32_16x16x32_bf16(a0, b2b[nt], acc2[0][nt], 0, 0, 0);
                    acc2[1][nt] = __builtin_amdgcn_mfma_f32_16x16x32_bf16(a1, b2b[nt], acc2[1][nt], 0, 0, 0);
                }
                __builtin_amdgcn_s_setprio(0);
            }
        }

        // ---------------- Epilogue: direct f32 stores --------------------------
        #pragma unroll
        for (int mt = 0; mt < 2; ++mt)
          #pragma unroll
          for (int r = 0; r < 4; ++r) {
            int flat = loc0 + mt * 16 + lg * 4 + r;
            float* op = out + (size_t)flat * EMB;
            #pragma unroll
            for (int nt = 0; nt < NT2; ++nt)
                op[(wv * NT2 + nt) * 16 + lr] = acc2[mt][nt][r];
          }

        if (!PERSIST) break;
    }
}

extern "C" void kernel_launch(void* const* d_in, const int* in_sizes, int n_in,
                              void* d_out, int out_size, void* d_ws, size_t ws_size,
                              hipStream_t stream) {
    const float* pix   = (const float*)d_in[0];
    const float* offw  = (const float*)d_in[1];
    const float* offb  = (const float*)d_in[2];
    const float* projw = (const float*)d_in[3];
    const float* projb = (const float*)d_in[4];
    float* out = (float*)d_out;
    uint16_t* wz = (uint16_t*)d_ws;

    const size_t ws_needed = CTR_OFF + 64;   // weights + tile counter

    if (ws_size >= ws_needed) {
        unsigned int* ctr = (unsigned int*)((char*)d_ws + CTR_OFF);
        hipMemsetAsync(ctr, 0, 4, stream);
        convert_weights<<<(W1_UNITS + W2_UNITS) / 256, 256, 0, stream>>>(offw, projw, wz);
        fused_kernel<true, true><<<PERSIST_BLOCKS, 512, 0, stream>>>(
            pix, offw, offb, projw, projb, wz, ctr, out);
    } else {
        fused_kernel<false, false><<<NTILES, 512, 0, stream>>>(
            pix, offw, offb, projw, projb, wz, nullptr, out);
    }
}

// Round 5
// 217.022 us; speedup vs baseline: 1.0680x; 1.0680x over previous
//
#include <hip/hip_runtime.h>
#include <stdint.h>

typedef __bf16 bf16x8 __attribute__((ext_vector_type(8)));
typedef float  f32x4  __attribute__((ext_vector_type(4)));

#define HH 384
#define WW 384
#define NPIX (HH*WW)
#define NC 3
#define NPATCH 576
#define EMB 768
#define PLEN 768
#define MLOC 64                  /* locations (rows) per block            */
#define KSTEPS 24
#define NLOC (64*576)
#define NTILES (NLOC/MLOC)       /* 576 */
#define NT1 2                    /* GEMM1 n-tiles per wave (16 x 2 = 32)  */
#define NT2 3                    /* GEMM2 n-tiles per wave (16 x 3 = 48)  */
#define W1_UNITS (32*KSTEPS*64)  /* 16B-units for offset weights */
#define W2_UNITS (48*KSTEPS*64)  /* 16B-units for proj weights   */
#define W2_OFF   (W1_UNITS*8)    /* u16 offset of w2 in ws       */
#define PXP_OFF  ((W1_UNITS+W2_UNITS)*8)   /* u16 offset of NHWC pixels */
#define NPIX_TOT (64*NPIX)

__device__ __forceinline__ uint16_t f2bf(float f) {
    uint32_t u = __builtin_bit_cast(uint32_t, f);
    u += 0x7FFFu + ((u >> 16) & 1u);
    return (uint16_t)(u >> 16);
}
__device__ __forceinline__ uint32_t pk2(float a, float b) {
    return (uint32_t)f2bf(a) | ((uint32_t)f2bf(b) << 16);
}
__device__ __forceinline__ float bf2f(uint16_t u) {
    return __builtin_bit_cast(float, (uint32_t)u << 16);
}

// Weights -> bf16 in MFMA-fragment order:
// unit u -> (nt, ks, lane); n = nt*16 + (lane&15), k = ks*32 + (lane>>4)*8 + e
__global__ __launch_bounds__(256)
void convert_weights(const float* __restrict__ offw, const float* __restrict__ projw,
                     uint16_t* __restrict__ wz) {
    int u = blockIdx.x * 256 + threadIdx.x;
    const float* src;
    int uu;
    if (u < W1_UNITS) { src = offw; uu = u; }
    else              { src = projw; uu = u - W1_UNITS; }
    int lane = uu & 63;
    int t    = uu >> 6;
    int ks   = t % KSTEPS;
    int nt   = t / KSTEPS;
    int n    = nt * 16 + (lane & 15);
    int k0   = ks * 32 + (lane >> 4) * 8;
    const float4* s4 = (const float4*)(src + (size_t)n * PLEN + k0);
    float4 v0 = s4[0], v1 = s4[1];
    uint4 w;
    w.x = pk2(v0.x, v0.y); w.y = pk2(v0.z, v0.w);
    w.z = pk2(v1.x, v1.y); w.w = pk2(v1.z, v1.w);
    *(uint4*)(wz + (size_t)u * 8) = w;
}

// NCHW f32 -> NHWC packed bf16 (ch0,ch1,ch2,pad) 8B per pixel
__global__ __launch_bounds__(256)
void nhwc_pass(const float* __restrict__ pix, uint16_t* __restrict__ pxp) {
    int idx = blockIdx.x * 256 + threadIdx.x;      // 0 .. NPIX_TOT-1
    int b  = idx / NPIX;
    int yx = idx - b * NPIX;
    const float* p = pix + (size_t)b * NC * NPIX + yx;
    uint2 w;
    w.x = pk2(p[0], p[NPIX]);
    w.y = (uint32_t)f2bf(p[2 * NPIX]);
    *(uint2*)(pxp + (size_t)idx * 4) = w;
}

template<bool USE_WS>
__global__ __launch_bounds__(1024, 4)
void fused_kernel(const float* __restrict__ pix,
                  const float* __restrict__ offw,
                  const float* __restrict__ offb,
                  const float* __restrict__ projw,
                  const float* __restrict__ projb,
                  const uint16_t* __restrict__ wz,
                  float* __restrict__ out) {
    __shared__ __align__(16) uint16_t As[MLOC][PLEN];   // 96 KB, XOR-swizzled rows

    const int tid  = threadIdx.x;
    const int wv   = tid >> 6;          // 0..15
    const int lane = tid & 63;
    const int lr   = lane & 15;
    const int lg   = lane >> 4;
    const int sw0  = (lr & 7) << 3;
    const int even = ((lane & 1) == 0);

    // bijective XCD swizzle: 576 blocks = 8 XCDs x 72
    int bid = (int)blockIdx.x;
    const int tile = (bid & 7) * 72 + (bid >> 3);

    const int loc0 = tile * MLOC;
    const int bimg = loc0 / NPATCH;
    const int p0   = loc0 - bimg * NPATCH;
    const float*    __restrict__ pb  = pix + (size_t)bimg * NC * NPIX;
    const uint16_t* __restrict__ pxp = wz + PXP_OFF + (size_t)bimg * NPIX * 4;

    // ---------------- Phase A: stage 64 patches (f32 -> bf16, swizzled) ----
    #pragma unroll
    for (int uu = 0; uu < 6; ++uu) {
        int unit = tid + uu * 1024;            // 0..6143 (64 loc x 96 units)
        int loc  = unit / 96;
        int k8   = (unit - loc * 96) * 8;
        int c  = k8 >> 8;
        int i  = (k8 >> 4) & 15;
        int j  = k8 & 15;
        int p  = p0 + loc;
        int ho = p / 24;
        int wo = p - ho * 24;
        const float* g = pb + ((size_t)c * HH + ho * 16 + i) * WW + wo * 16 + j;
        float4 v0 = *(const float4*)g;
        float4 v1 = *(const float4*)(g + 4);
        uint4 w;
        w.x = pk2(v0.x, v0.y); w.y = pk2(v0.z, v0.w);
        w.z = pk2(v1.x, v1.y); w.w = pk2(v1.z, v1.w);
        *(uint4*)&As[loc][k8 ^ ((loc & 7) << 3)] = w;
    }

    // ---------------- GEMM1: offsets [64 x 512], B double-buffered ---------
    auto ldb1 = [&](int ntg, int ks) -> bf16x8 {
        if (USE_WS) {
            return *(const bf16x8*)(wz + ((size_t)((ntg * KSTEPS + ks) * 64 + lane)) * 8);
        } else {
            int n = ntg * 16 + lr;
            const float4* s4 = (const float4*)(offw + (size_t)n * PLEN + ks * 32 + lg * 8);
            float4 v0 = s4[0], v1 = s4[1];
            uint4 uq = {pk2(v0.x,v0.y), pk2(v0.z,v0.w), pk2(v1.x,v1.y), pk2(v1.z,v1.w)};
            return __builtin_bit_cast(bf16x8, uq);
        }
    };
    bf16x8 b1a[NT1], b1b[NT1];
    #pragma unroll
    for (int nt = 0; nt < NT1; ++nt) b1a[nt] = ldb1(wv * NT1 + nt, 0);
    __syncthreads();                       // stage visible

    f32x4 acc1[4][NT1];
    #pragma unroll
    for (int nt = 0; nt < NT1; ++nt) {
        float bz = offb[(wv * NT1 + nt) * 16 + lr];
        f32x4 z = {bz, bz, bz, bz};
        #pragma unroll
        for (int mt = 0; mt < 4; ++mt) acc1[mt][nt] = z;
    }
    #pragma unroll 1
    for (int ks2 = 0; ks2 < KSTEPS / 2; ++ks2) {
        const int ks0 = ks2 * 2;
        {
            #pragma unroll
            for (int nt = 0; nt < NT1; ++nt) b1b[nt] = ldb1(wv * NT1 + nt, ks0 + 1);
            int ke = (ks0 * 32 + lg * 8) ^ sw0;
            bf16x8 a0 = *(const bf16x8*)&As[     lr][ke];
            bf16x8 a1 = *(const bf16x8*)&As[16 + lr][ke];
            bf16x8 a2 = *(const bf16x8*)&As[32 + lr][ke];
            bf16x8 a3 = *(const bf16x8*)&As[48 + lr][ke];
            __builtin_amdgcn_s_setprio(1);
            #pragma unroll
            for (int nt = 0; nt < NT1; ++nt) {
                acc1[0][nt] = __builtin_amdgcn_mfma_f32_16x16x32_bf16(a0, b1a[nt], acc1[0][nt], 0, 0, 0);
                acc1[1][nt] = __builtin_amdgcn_mfma_f32_16x16x32_bf16(a1, b1a[nt], acc1[1][nt], 0, 0, 0);
                acc1[2][nt] = __builtin_amdgcn_mfma_f32_16x16x32_bf16(a2, b1a[nt], acc1[2][nt], 0, 0, 0);
                acc1[3][nt] = __builtin_amdgcn_mfma_f32_16x16x32_bf16(a3, b1a[nt], acc1[3][nt], 0, 0, 0);
            }
            __builtin_amdgcn_s_setprio(0);
        }
        {
            int ksn = (ks0 + 2 < KSTEPS) ? ks0 + 2 : 0;
            #pragma unroll
            for (int nt = 0; nt < NT1; ++nt) b1a[nt] = ldb1(wv * NT1 + nt, ksn);
            int ke = ((ks0 + 1) * 32 + lg * 8) ^ sw0;
            bf16x8 a0 = *(const bf16x8*)&As[     lr][ke];
            bf16x8 a1 = *(const bf16x8*)&As[16 + lr][ke];
            bf16x8 a2 = *(const bf16x8*)&As[32 + lr][ke];
            bf16x8 a3 = *(const bf16x8*)&As[48 + lr][ke];
            __builtin_amdgcn_s_setprio(1);
            #pragma unroll
            for (int nt = 0; nt < NT1; ++nt) {
                acc1[0][nt] = __builtin_amdgcn_mfma_f32_16x16x32_bf16(a0, b1b[nt], acc1[0][nt], 0, 0, 0);
                acc1[1][nt] = __builtin_amdgcn_mfma_f32_16x16x32_bf16(a1, b1b[nt], acc1[1][nt], 0, 0, 0);
                acc1[2][nt] = __builtin_amdgcn_mfma_f32_16x16x32_bf16(a2, b1b[nt], acc1[2][nt], 0, 0, 0);
                acc1[3][nt] = __builtin_amdgcn_mfma_f32_16x16x32_bf16(a3, b1b[nt], acc1[3][nt], 0, 0, 0);
            }
            __builtin_amdgcn_s_setprio(0);
        }
    }
    __syncthreads();   // all waves done reading patch A-matrix

    // ---------------- Pair (dy,dx) in-register via shfl_xor ----------------
    // D: col n = (wv*NT1+nt)*16 + lr, row = mt*16 + lg*4 + r. n=2q dy, 2q+1 dx.
    // Even lanes own nt=0, odd lanes nt=1.
    float dyg[4][4], dxg[4][4];
    #pragma unroll
    for (int nt = 0; nt < NT1; ++nt)
      #pragma unroll
      for (int mt = 0; mt < 4; ++mt)
        #pragma unroll
        for (int r = 0; r < 4; ++r) {
            float v  = acc1[mt][nt][r];
            float pv = __shfl_xor(v, 1);
            if ((nt == 0) == (even != 0)) {
                dyg[mt][r] = even ? v  : pv;
                dxg[mt][r] = even ? pv : v;
            }
        }

    // ---------------- Phase C: bilinear gather (NHWC bf16) -> As -----------
    const int ntb  = wv * NT1 + (even ? 0 : 1);
    const int qlow = lr >> 1;
    const int q    = ntb * 8 + qlow;       // patch pixel 0..255
    const int qi   = q >> 4;
    const int qj   = q & 15;
    #pragma unroll
    for (int mt = 0; mt < 4; ++mt)
      #pragma unroll
      for (int r = 0; r < 4; ++r) {
        int locl = mt * 16 + lg * 4 + r;
        int p  = p0 + locl;
        int ho = p / 24;
        int wo = p - ho * 24;
        float py = (float)(ho * 16 + qi) + dyg[mt][r];
        float px = (float)(wo * 16 + qj) + dxg[mt][r];
        float y0f = floorf(py), x0f = floorf(px);
        float wy1 = py - y0f, wy0 = 1.f - wy1;
        float wx1 = px - x0f, wx0 = 1.f - wx1;
        int y0 = (int)y0f, x0 = (int)x0f;
        float s0 = 0.f, s1 = 0.f, s2 = 0.f;
        #pragma unroll
        for (int cy = 0; cy < 2; ++cy) {
            int yy = y0 + cy;
            if ((unsigned)yy < (unsigned)HH) {
                float wy = cy ? wy1 : wy0;
                #pragma unroll
                for (int cx = 0; cx < 2; ++cx) {
                    int xx = x0 + cx;
                    if ((unsigned)xx < (unsigned)WW) {
                        float w = wy * (cx ? wx1 : wx0);
                        float v0, v1, v2;
                        if (USE_WS) {
                            uint2 d = *(const uint2*)(pxp + ((size_t)yy * WW + xx) * 4);
                            v0 = bf2f((uint16_t)d.x);
                            v1 = bf2f((uint16_t)(d.x >> 16));
                            v2 = bf2f((uint16_t)d.y);
                        } else {
                            const float* cp = pb + yy * WW + xx;
                            v0 = cp[0]; v1 = cp[NPIX]; v2 = cp[2 * NPIX];
                        }
                        s0 += w * v0; s1 += w * v1; s2 += w * v2;
                    }
                }
            }
        }
        int swl = (locl & 7) << 3;
        As[locl][(      q) ^ swl] = f2bf(s0);
        As[locl][(256 + q) ^ swl] = f2bf(s1);
        As[locl][(512 + q) ^ swl] = f2bf(s2);
      }

    // ---------------- GEMM2: out [64 x 768], B double-buffered -------------
    auto ldb2 = [&](int ntg, int ks) -> bf16x8 {
        if (USE_WS) {
            return *(const bf16x8*)(wz + W2_OFF + ((size_t)((ntg * KSTEPS + ks) * 64 + lane)) * 8);
        } else {
            int n = ntg * 16 + lr;
            const float4* s4 = (const float4*)(projw + (size_t)n * PLEN + ks * 32 + lg * 8);
            float4 v0 = s4[0], v1 = s4[1];
            uint4 uq = {pk2(v0.x,v0.y), pk2(v0.z,v0.w), pk2(v1.x,v1.y), pk2(v1.z,v1.w)};
            return __builtin_bit_cast(bf16x8, uq);
        }
    };
    bf16x8 b2a[NT2], b2b[NT2];
    #pragma unroll
    for (int nt = 0; nt < NT2; ++nt) b2a[nt] = ldb2(wv * NT2 + nt, 0);
    __syncthreads();                       // sampled writes visible

    f32x4 acc2[4][NT2];
    #pragma unroll
    for (int nt = 0; nt < NT2; ++nt) {
        float bz = projb[(wv * NT2 + nt) * 16 + lr];
        f32x4 z = {bz, bz, bz, bz};
        #pragma unroll
        for (int mt = 0; mt < 4; ++mt) acc2[mt][nt] = z;
    }
    #pragma unroll 1
    for (int ks2 = 0; ks2 < KSTEPS / 2; ++ks2) {
        const int ks0 = ks2 * 2;
        {
            #pragma unroll
            for (int nt = 0; nt < NT2; ++nt) b2b[nt] = ldb2(wv * NT2 + nt, ks0 + 1);
            int ke = (ks0 * 32 + lg * 8) ^ sw0;
            bf16x8 a0 = *(const bf16x8*)&As[     lr][ke];
            bf16x8 a1 = *(const bf16x8*)&As[16 + lr][ke];
            bf16x8 a2 = *(const bf16x8*)&As[32 + lr][ke];
            bf16x8 a3 = *(const bf16x8*)&As[48 + lr][ke];
            __builtin_amdgcn_s_setprio(1);
            #pragma unroll
            for (int nt = 0; nt < NT2; ++nt) {
                acc2[0][nt] = __builtin_amdgcn_mfma_f32_16x16x32_bf16(a0, b2a[nt], acc2[0][nt], 0, 0, 0);
                acc2[1][nt] = __builtin_amdgcn_mfma_f32_16x16x32_bf16(a1, b2a[nt], acc2[1][nt], 0, 0, 0);
                acc2[2][nt] = __builtin_amdgcn_mfma_f32_16x16x32_bf16(a2, b2a[nt], acc2[2][nt], 0, 0, 0);
                acc2[3][nt] = __builtin_amdgcn_mfma_f32_16x16x32_bf16(a3, b2a[nt], acc2[3][nt], 0, 0, 0);
            }
            __builtin_amdgcn_s_setprio(0);
        }
        {
            int ksn = (ks0 + 2 < KSTEPS) ? ks0 + 2 : 0;
            #pragma unroll
            for (int nt = 0; nt < NT2; ++nt) b2a[nt] = ldb2(wv * NT2 + nt, ksn);
            int ke = ((ks0 + 1) * 32 + lg * 8) ^ sw0;
            bf16x8 a0 = *(const bf16x8*)&As[     lr][ke];
            bf16x8 a1 = *(const bf16x8*)&As[16 + lr][ke];
            bf16x8 a2 = *(const bf16x8*)&As[32 + lr][ke];
            bf16x8 a3 = *(const bf16x8*)&As[48 + lr][ke];
            __builtin_amdgcn_s_setprio(1);
            #pragma unroll
            for (int nt = 0; nt < NT2; ++nt) {
                acc2[0][nt] = __builtin_amdgcn_mfma_f32_16x16x32_bf16(a0, b2b[nt], acc2[0][nt], 0, 0, 0);
                acc2[1][nt] = __builtin_amdgcn_mfma_f32_16x16x32_bf16(a1, b2b[nt], acc2[1][nt], 0, 0, 0);
                acc2[2][nt] = __builtin_amdgcn_mfma_f32_16x16x32_bf16(a2, b2b[nt], acc2[2][nt], 0, 0, 0);
                acc2[3][nt] = __builtin_amdgcn_mfma_f32_16x16x32_bf16(a3, b2b[nt], acc2[3][nt], 0, 0, 0);
            }
            __builtin_amdgcn_s_setprio(0);
        }
    }

    // ---------------- Epilogue: direct f32 stores --------------------------
    #pragma unroll
    for (int mt = 0; mt < 4; ++mt)
      #pragma unroll
      for (int r = 0; r < 4; ++r) {
        int flat = loc0 + mt * 16 + lg * 4 + r;
        float* op = out + (size_t)flat * EMB;
        #pragma unroll
        for (int nt = 0; nt < NT2; ++nt)
            op[(wv * NT2 + nt) * 16 + lr] = acc2[mt][nt][r];
      }
}

extern "C" void kernel_launch(void* const* d_in, const int* in_sizes, int n_in,
                              void* d_out, int out_size, void* d_ws, size_t ws_size,
                              hipStream_t stream) {
    const float* pix   = (const float*)d_in[0];
    const float* offw  = (const float*)d_in[1];
    const float* offb  = (const float*)d_in[2];
    const float* projw = (const float*)d_in[3];
    const float* projb = (const float*)d_in[4];
    float* out = (float*)d_out;
    uint16_t* wz = (uint16_t*)d_ws;

    const size_t ws_needed = (size_t)(W1_UNITS + W2_UNITS) * 16 + (size_t)NPIX_TOT * 8;

    if (ws_size >= ws_needed) {
        convert_weights<<<(W1_UNITS + W2_UNITS) / 256, 256, 0, stream>>>(offw, projw, wz);
        nhwc_pass<<<NPIX_TOT / 256, 256, 0, stream>>>(pix, wz + PXP_OFF);
        fused_kernel<true><<<NTILES, 1024, 0, stream>>>(pix, offw, offb, projw, projb, wz, out);
    } else {
        fused_kernel<false><<<NTILES, 1024, 0, stream>>>(pix, offw, offb, projw, projb, wz, out);
    }
}

// Round 6
// 214.722 us; speedup vs baseline: 1.0794x; 1.0107x over previous
//
#include <hip/hip_runtime.h>
#include <stdint.h>

typedef __bf16 bf16x8 __attribute__((ext_vector_type(8)));
typedef float  f32x4  __attribute__((ext_vector_type(4)));

#define HH 384
#define WW 384
#define NPIX (HH*WW)
#define NC 3
#define NPATCH 576
#define EMB 768
#define PLEN 768
#define MLOC 32
#define KSTEPS 24
#define NLOC (64*576)
#define NTILES (NLOC/MLOC)       /* 1152 */
#define NT1 4                    /* GEMM1 n-tiles per wave (8 waves x 4 = 32) */
#define NT2 6                    /* GEMM2 n-tiles per wave (8 waves x 6 = 48) */
#define W1_UNITS (32*KSTEPS*64)
#define W2_UNITS (48*KSTEPS*64)
#define W2_OFF   (W1_UNITS*8)
#define PXP_OFF  ((W1_UNITS+W2_UNITS)*8)
#define NPIX_TOT (64*NPIX)
#define WBLKS  ((W1_UNITS + W2_UNITS) / 256)   /* 480  */
#define PXBLKS (NPIX_TOT / (256*4))            /* 36864 */

__device__ __forceinline__ uint16_t f2bf(float f) {
    uint32_t u = __builtin_bit_cast(uint32_t, f);
    u += 0x7FFFu + ((u >> 16) & 1u);
    return (uint16_t)(u >> 16);
}
__device__ __forceinline__ uint32_t pk2(float a, float b) {
    return (uint32_t)f2bf(a) | ((uint32_t)f2bf(b) << 16);
}
__device__ __forceinline__ float bf2f(uint16_t u) {
    return __builtin_bit_cast(float, (uint32_t)u << 16);
}

// Fused pre-pass: blocks [0,WBLKS) convert weights to MFMA-fragment bf16;
// blocks [WBLKS, WBLKS+PXBLKS) pack pixels NCHW f32 -> NHWC bf16 (8B/px).
__global__ __launch_bounds__(256)
void prepass(const float* __restrict__ offw, const float* __restrict__ projw,
             const float* __restrict__ pix, uint16_t* __restrict__ wz) {
    int b = blockIdx.x;
    if (b < WBLKS) {
        int u = b * 256 + threadIdx.x;
        const float* src;
        int uu;
        if (u < W1_UNITS) { src = offw; uu = u; }
        else              { src = projw; uu = u - W1_UNITS; }
        int lane = uu & 63;
        int t    = uu >> 6;
        int ks   = t % KSTEPS;
        int nt   = t / KSTEPS;
        int n    = nt * 16 + (lane & 15);
        int k0   = ks * 32 + (lane >> 4) * 8;
        const float4* s4 = (const float4*)(src + (size_t)n * PLEN + k0);
        float4 v0 = s4[0], v1 = s4[1];
        uint4 w;
        w.x = pk2(v0.x, v0.y); w.y = pk2(v0.z, v0.w);
        w.z = pk2(v1.x, v1.y); w.w = pk2(v1.z, v1.w);
        *(uint4*)(wz + (size_t)u * 8) = w;
    } else {
        int idx  = (b - WBLKS) * 256 + threadIdx.x;   // 4-pixel group
        int base = idx * 4;
        int im = base / NPIX;
        int yx = base - im * NPIX;                    // NPIX % 4 == 0
        const float* p = pix + (size_t)im * NC * NPIX + yx;
        float4 c0 = *(const float4*)p;
        float4 c1 = *(const float4*)(p + NPIX);
        float4 c2 = *(const float4*)(p + 2 * NPIX);
        uint4 o0, o1;
        o0.x = pk2(c0.x, c1.x); o0.y = (uint32_t)f2bf(c2.x);
        o0.z = pk2(c0.y, c1.y); o0.w = (uint32_t)f2bf(c2.y);
        o1.x = pk2(c0.z, c1.z); o1.y = (uint32_t)f2bf(c2.z);
        o1.z = pk2(c0.w, c1.w); o1.w = (uint32_t)f2bf(c2.w);
        uint16_t* dst = wz + PXP_OFF + (size_t)base * 4;
        *(uint4*)dst       = o0;
        *(uint4*)(dst + 8) = o1;
    }
}

template<bool USE_WS>
__global__ __launch_bounds__(512, 4)
void fused_kernel(const float* __restrict__ pix,
                  const float* __restrict__ offw,
                  const float* __restrict__ offb,
                  const float* __restrict__ projw,
                  const float* __restrict__ projb,
                  const uint16_t* __restrict__ wz,
                  float* __restrict__ out) {
    __shared__ __align__(16) uint16_t As[MLOC][PLEN];   // 48 KB, XOR-swizzled rows
    __shared__ uint32_t Offs[MLOC][256];                // 32 KB packed (dy,dx) bf16

    const int tid  = threadIdx.x;
    const int wv   = tid >> 6;
    const int lane = tid & 63;
    const int lr   = lane & 15;
    const int lg   = lane >> 4;
    const int sw0  = (lr & 7) << 3;
    const int even = ((lane & 1) == 0);

    // bijective XCD swizzle: 1152 = 8 x 144
    int bid = (int)blockIdx.x;
    const int tile = (bid & 7) * 144 + (bid >> 3);

    const int loc0 = tile * MLOC;
    const int bimg = loc0 / NPATCH;
    const int p0   = loc0 - bimg * NPATCH;
    const float*    __restrict__ pb  = pix + (size_t)bimg * NC * NPIX;
    const uint16_t* __restrict__ pxp = wz + PXP_OFF + (size_t)bimg * NPIX * 4;

    // ---------------- Phase A: stage 32 patches (f32 -> bf16, swizzled) ----
    #pragma unroll
    for (int uu = 0; uu < 6; ++uu) {
        int unit = tid + uu * 512;             // 0..3071
        int loc  = unit / 96;
        int k8   = (unit - loc * 96) * 8;
        int c  = k8 >> 8;
        int i  = (k8 >> 4) & 15;
        int j  = k8 & 15;
        int p  = p0 + loc;
        int ho = p / 24;
        int wo = p - ho * 24;
        const float* g = pb + ((size_t)c * HH + ho * 16 + i) * WW + wo * 16 + j;
        float4 v0 = *(const float4*)g;
        float4 v1 = *(const float4*)(g + 4);
        uint4 w;
        w.x = pk2(v0.x, v0.y); w.y = pk2(v0.z, v0.w);
        w.z = pk2(v1.x, v1.y); w.w = pk2(v1.z, v1.w);
        *(uint4*)&As[loc][k8 ^ ((loc & 7) << 3)] = w;
    }

    // ---------------- GEMM1: offsets [32 x 512], B double-buffered ---------
    auto ldb1 = [&](int ntg, int ks) -> bf16x8 {
        if (USE_WS) {
            return *(const bf16x8*)(wz + ((size_t)((ntg * KSTEPS + ks) * 64 + lane)) * 8);
        } else {
            int n = ntg * 16 + lr;
            const float4* s4 = (const float4*)(offw + (size_t)n * PLEN + ks * 32 + lg * 8);
            float4 v0 = s4[0], v1 = s4[1];
            uint4 uq = {pk2(v0.x,v0.y), pk2(v0.z,v0.w), pk2(v1.x,v1.y), pk2(v1.z,v1.w)};
            return __builtin_bit_cast(bf16x8, uq);
        }
    };
    bf16x8 b1a[NT1], b1b[NT1];
    #pragma unroll
    for (int nt = 0; nt < NT1; ++nt) b1a[nt] = ldb1(wv * NT1 + nt, 0);
    __syncthreads();                       // stage visible

    f32x4 acc1[2][NT1];
    #pragma unroll
    for (int nt = 0; nt < NT1; ++nt) {
        float bz = offb[(wv * NT1 + nt) * 16 + lr];
        f32x4 z = {bz, bz, bz, bz};
        acc1[0][nt] = z; acc1[1][nt] = z;
    }
    #pragma unroll 1
    for (int ks2 = 0; ks2 < KSTEPS / 2; ++ks2) {
        const int ks0 = ks2 * 2;
        {
            #pragma unroll
            for (int nt = 0; nt < NT1; ++nt) b1b[nt] = ldb1(wv * NT1 + nt, ks0 + 1);
            int ke = (ks0 * 32 + lg * 8) ^ sw0;
            bf16x8 a0 = *(const bf16x8*)&As[lr][ke];
            bf16x8 a1 = *(const bf16x8*)&As[16 + lr][ke];
            __builtin_amdgcn_s_setprio(1);
            #pragma unroll
            for (int nt = 0; nt < NT1; ++nt) {
                acc1[0][nt] = __builtin_amdgcn_mfma_f32_16x16x32_bf16(a0, b1a[nt], acc1[0][nt], 0, 0, 0);
                acc1[1][nt] = __builtin_amdgcn_mfma_f32_16x16x32_bf16(a1, b1a[nt], acc1[1][nt], 0, 0, 0);
            }
            __builtin_amdgcn_s_setprio(0);
        }
        {
            int ksn = (ks0 + 2 < KSTEPS) ? ks0 + 2 : 0;
            #pragma unroll
            for (int nt = 0; nt < NT1; ++nt) b1a[nt] = ldb1(wv * NT1 + nt, ksn);
            int ke = ((ks0 + 1) * 32 + lg * 8) ^ sw0;
            bf16x8 a0 = *(const bf16x8*)&As[lr][ke];
            bf16x8 a1 = *(const bf16x8*)&As[16 + lr][ke];
            __builtin_amdgcn_s_setprio(1);
            #pragma unroll
            for (int nt = 0; nt < NT1; ++nt) {
                acc1[0][nt] = __builtin_amdgcn_mfma_f32_16x16x32_bf16(a0, b1b[nt], acc1[0][nt], 0, 0, 0);
                acc1[1][nt] = __builtin_amdgcn_mfma_f32_16x16x32_bf16(a1, b1b[nt], acc1[1][nt], 0, 0, 0);
            }
            __builtin_amdgcn_s_setprio(0);
        }
    }

    // ---------------- Scatter (dy,dx) -> Offs LDS (bf16-packed) ------------
    // acc1 D layout: col n = (wv*NT1+nt)*16 + lr, row = mt*16 + lg*4 + r.
    // n=2q dy(q), n=2q+1 dx(q); shfl_xor(1) pairs them; even lanes own
    // sub-tiles {0,1}, odd {2,3}.
    #pragma unroll
    for (int nt = 0; nt < NT1; ++nt)
      #pragma unroll
      for (int mt = 0; mt < 2; ++mt)
        #pragma unroll
        for (int r = 0; r < 4; ++r) {
            float v  = acc1[mt][nt][r];
            float pv = __shfl_xor(v, 1);
            if ((nt < 2) == (even != 0)) {
                int s   = nt & 1;
                int loc = mt * 16 + lg * 4 + r;
                int q   = (wv * NT1 + (even ? 0 : 2) + s) * 8 + (lr >> 1);
                float dy = even ? v  : pv;
                float dx = even ? pv : v;
                Offs[loc][q] = pk2(dy, dx);
            }
        }
    __syncthreads();   // As reads done (safe to overwrite) + Offs visible

    // ---------------- Phase C: locality-mapped gather ----------------------
    // Wave wv owns patches L = wv*4 .. wv*4+3. Lanes cover 64 CONTIGUOUS
    // sample positions (4 patch rows x 16 cols) -> compact pixel footprint.
    {
        #pragma unroll
        for (int li = 0; li < 4; ++li) {
            const int L  = wv * 4 + li;
            const int p  = p0 + L;
            const int ho = p / 24;
            const int wo = p - ho * 24;           // wave-uniform (SGPR)
            const int swl = (L & 7) << 3;
            const int by = ho * 16;
            const int bx = wo * 16;
            #pragma unroll
            for (int s4 = 0; s4 < 4; ++s4) {
                const int q  = s4 * 64 + lane;
                const int qi = q >> 4;
                const int qj = q & 15;
                uint32_t od = Offs[L][q];
                float dy = bf2f((uint16_t)od);
                float dx = bf2f((uint16_t)(od >> 16));
                float py = (float)(by + qi) + dy;
                float px = (float)(bx + qj) + dx;
                float y0f = floorf(py), x0f = floorf(px);
                float wy1 = py - y0f, wy0 = 1.f - wy1;
                float wx1 = px - x0f, wx0 = 1.f - wx1;
                int y0 = (int)y0f, x0 = (int)x0f;
                float s0 = 0.f, s1 = 0.f, s2 = 0.f;
                #pragma unroll
                for (int cy = 0; cy < 2; ++cy) {
                    int yy = y0 + cy;
                    if ((unsigned)yy < (unsigned)HH) {
                        float wy = cy ? wy1 : wy0;
                        #pragma unroll
                        for (int cx = 0; cx < 2; ++cx) {
                            int xx = x0 + cx;
                            if ((unsigned)xx < (unsigned)WW) {
                                float w = wy * (cx ? wx1 : wx0);
                                float v0, v1, v2;
                                if (USE_WS) {
                                    uint2 d = *(const uint2*)(pxp + ((size_t)yy * WW + xx) * 4);
                                    v0 = bf2f((uint16_t)d.x);
                                    v1 = bf2f((uint16_t)(d.x >> 16));
                                    v2 = bf2f((uint16_t)d.y);
                                } else {
                                    const float* cp = pb + yy * WW + xx;
                                    v0 = cp[0]; v1 = cp[NPIX]; v2 = cp[2 * NPIX];
                                }
                                s0 += w * v0; s1 += w * v1; s2 += w * v2;
                            }
                        }
                    }
                }
                As[L][(      q) ^ swl] = f2bf(s0);
                As[L][(256 + q) ^ swl] = f2bf(s1);
                As[L][(512 + q) ^ swl] = f2bf(s2);
            }
        }
    }

    // ---------------- GEMM2: out [32 x 768], B double-buffered -------------
    auto ldb2 = [&](int ntg, int ks) -> bf16x8 {
        if (USE_WS) {
            return *(const bf16x8*)(wz + W2_OFF + ((size_t)((ntg * KSTEPS + ks) * 64 + lane)) * 8);
        } else {
            int n = ntg * 16 + lr;
            const float4* s4 = (const float4*)(projw + (size_t)n * PLEN + ks * 32 + lg * 8);
            float4 v0 = s4[0], v1 = s4[1];
            uint4 uq = {pk2(v0.x,v0.y), pk2(v0.z,v0.w), pk2(v1.x,v1.y), pk2(v1.z,v1.w)};
            return __builtin_bit_cast(bf16x8, uq);
        }
    };
    bf16x8 b2a[NT2], b2b[NT2];
    #pragma unroll
    for (int nt = 0; nt < NT2; ++nt) b2a[nt] = ldb2(wv * NT2 + nt, 0);
    __syncthreads();                       // sampled writes visible

    f32x4 acc2[2][NT2];
    #pragma unroll
    for (int nt = 0; nt < NT2; ++nt) {
        float bz = projb[(wv * NT2 + nt) * 16 + lr];
        f32x4 z = {bz, bz, bz, bz};
        acc2[0][nt] = z; acc2[1][nt] = z;
    }
    #pragma unroll 1
    for (int ks2 = 0; ks2 < KSTEPS / 2; ++ks2) {
        const int ks0 = ks2 * 2;
        {
            #pragma unroll
            for (int nt = 0; nt < NT2; ++nt) b2b[nt] = ldb2(wv * NT2 + nt, ks0 + 1);
            int ke = (ks0 * 32 + lg * 8) ^ sw0;
            bf16x8 a0 = *(const bf16x8*)&As[lr][ke];
            bf16x8 a1 = *(const bf16x8*)&As[16 + lr][ke];
            __builtin_amdgcn_s_setprio(1);
            #pragma unroll
            for (int nt = 0; nt < NT2; ++nt) {
                acc2[0][nt] = __builtin_amdgcn_mfma_f32_16x16x32_bf16(a0, b2a[nt], acc2[0][nt], 0, 0, 0);
                acc2[1][nt] = __builtin_amdgcn_mfma_f32_16x16x32_bf16(a1, b2a[nt], acc2[1][nt], 0, 0, 0);
            }
            __builtin_amdgcn_s_setprio(0);
        }
        {
            int ksn = (ks0 + 2 < KSTEPS) ? ks0 + 2 : 0;
            #pragma unroll
            for (int nt = 0; nt < NT2; ++nt) b2a[nt] = ldb2(wv * NT2 + nt, ksn);
            int ke = ((ks0 + 1) * 32 + lg * 8) ^ sw0;
            bf16x8 a0 = *(const bf16x8*)&As[lr][ke];
            bf16x8 a1 = *(const bf16x8*)&As[16 + lr][ke];
            __builtin_amdgcn_s_setprio(1);
            #pragma unroll
            for (int nt = 0; nt < NT2; ++nt) {
                acc2[0][nt] = __builtin_amdgcn_mfma_f32_16x16x32_bf16(a0, b2b[nt], acc2[0][nt], 0, 0, 0);
                acc2[1][nt] = __builtin_amdgcn_mfma_f32_16x16x32_bf16(a1, b2b[nt], acc2[1][nt], 0, 0, 0);
            }
            __builtin_amdgcn_s_setprio(0);
        }
    }

    // ---------------- Epilogue: direct f32 stores --------------------------
    #pragma unroll
    for (int mt = 0; mt < 2; ++mt)
      #pragma unroll
      for (int r = 0; r < 4; ++r) {
        int flat = loc0 + mt * 16 + lg * 4 + r;
        float* op = out + (size_t)flat * EMB;
        #pragma unroll
        for (int nt = 0; nt < NT2; ++nt)
            op[(wv * NT2 + nt) * 16 + lr] = acc2[mt][nt][r];
      }
}

extern "C" void kernel_launch(void* const* d_in, const int* in_sizes, int n_in,
                              void* d_out, int out_size, void* d_ws, size_t ws_size,
                              hipStream_t stream) {
    const float* pix   = (const float*)d_in[0];
    const float* offw  = (const float*)d_in[1];
    const float* offb  = (const float*)d_in[2];
    const float* projw = (const float*)d_in[3];
    const float* projb = (const float*)d_in[4];
    float* out = (float*)d_out;
    uint16_t* wz = (uint16_t*)d_ws;

    const size_t ws_needed = (size_t)(W1_UNITS + W2_UNITS) * 16 + (size_t)NPIX_TOT * 8;

    if (ws_size >= ws_needed) {
        prepass<<<WBLKS + PXBLKS, 256, 0, stream>>>(offw, projw, pix, wz);
        fused_kernel<true><<<NTILES, 512, 0, stream>>>(pix, offw, offb, projw, projb, wz, out);
    } else {
        fused_kernel<false><<<NTILES, 512, 0, stream>>>(pix, offw, offb, projw, projb, wz, out);
    }
}